// Round 16
// baseline (395.851 us; speedup 1.0000x reference)
//
#include <hip/hip_runtime.h>
#include <math.h>

#define B_   8
#define T_   256
#define U_   64
#define UP1  65
#define DE   640
#define J_   512
#define V_   1024
#define NCELL (B_ * T_ * UP1)
#define LOG0 -1e30f

typedef __attribute__((ext_vector_type(4))) float f32x4;

// ---------------- DPP wave64 scan/reduce helpers -------------------------------------
template<int CTRL, int RM>
__device__ __forceinline__ float dppz(float x) {
    return __builtin_bit_cast(float,
        __builtin_amdgcn_update_dpp(0, __builtin_bit_cast(int, x), CTRL, RM, 0xf, false));
}
template<int CTRL, int RM>
__device__ __forceinline__ float dpps(float x) {
    int xi = __builtin_bit_cast(int, x);
    return __builtin_bit_cast(float,
        __builtin_amdgcn_update_dpp(xi, xi, CTRL, RM, 0xf, false));
}
__device__ __forceinline__ float wave_prefix_sum(float v) {
    v += dppz<0x111, 0xf>(v);
    v += dppz<0x112, 0xf>(v);
    v += dppz<0x114, 0xf>(v);
    v += dppz<0x118, 0xf>(v);
    v += dppz<0x142, 0xa>(v);
    v += dppz<0x143, 0xc>(v);
    return v;
}
__device__ __forceinline__ float wave_max_all(float v) {
    v = fmaxf(v, dpps<0x111, 0xf>(v));
    v = fmaxf(v, dpps<0x112, 0xf>(v));
    v = fmaxf(v, dpps<0x114, 0xf>(v));
    v = fmaxf(v, dpps<0x118, 0xf>(v));
    v = fmaxf(v, dpps<0x142, 0xa>(v));
    v = fmaxf(v, dpps<0x143, 0xc>(v));
    return __builtin_bit_cast(float,
        __builtin_amdgcn_readlane(__builtin_bit_cast(int, v), 63));
}
__device__ __forceinline__ float rdlane(float v, int l) {
    return __builtin_bit_cast(float,
        __builtin_amdgcn_readlane(__builtin_bit_cast(int, v), l));
}

// LDS swizzle for fp8 hB: row m (512B rows), cb = column byte offset (8B granular).
__device__ __forceinline__ unsigned hb8(unsigned m, unsigned cb) {
    return m * 512u + (cb ^ ((m & 15u) << 3));
}

// ------- Kernel A: C[M x 512] = A[M x 640] * W[640 x 512] (+bias), 32x64 tiles --------
__global__ __launch_bounds__(256) void gemm_in(const float* __restrict__ A,
                                               const float* __restrict__ W,
                                               const float* __restrict__ bias,
                                               float* __restrict__ C, int M) {
    __shared__ float As[16][32];
    __shared__ float Bs[16][64];
    int tid  = threadIdx.x;
    int row0 = blockIdx.x * 32;
    int col0 = blockIdx.y * 64;
    int tx = tid & 15, ty = tid >> 4;
    float acc[2][4] = {};
    int ar  = tid >> 3;
    int ak2 = (tid & 7) * 2;
    int bkr = tid >> 4;
    int bcq = tid & 15;
    for (int k0 = 0; k0 < DE; k0 += 16) {
        float2 av = make_float2(0.f, 0.f);
        int arow = row0 + ar;
        if (arow < M) av = *(const float2*)&A[arow * DE + k0 + ak2];
        As[ak2][ar]     = av.x;
        As[ak2 + 1][ar] = av.y;
        *(float4*)&Bs[bkr][bcq * 4] = *(const float4*)&W[(k0 + bkr) * J_ + col0 + bcq * 4];
        __syncthreads();
#pragma unroll
        for (int k = 0; k < 16; ++k) {
            float a0 = As[k][ty * 2], a1 = As[k][ty * 2 + 1];
            float4 b4 = *(const float4*)&Bs[k][tx * 4];
            float b[4] = {b4.x, b4.y, b4.z, b4.w};
#pragma unroll
            for (int j = 0; j < 4; ++j) {
                acc[0][j] += a0 * b[j];
                acc[1][j] += a1 * b[j];
            }
        }
        __syncthreads();
    }
#pragma unroll
    for (int i = 0; i < 2; ++i) {
        int row = row0 + ty * 2 + i;
        if (row >= M) continue;
#pragma unroll
        for (int j = 0; j < 4; ++j) {
            int col = col0 + tx * 4 + j;
            float v = acc[i][j];
            if (bias) v += bias[col];
            C[row * J_ + col] = v;
        }
    }
}

// ---- Kernel W: W_out[512][1024] -> fragment-major fp8(e4m3) Wf (round-6 K32 layout) --
__global__ __launch_bounds__(256) void wt_kernel(const float* __restrict__ W,
                                                 unsigned char* __restrict__ Wf) {
    __shared__ float tile[32][33];
    int tid = threadIdx.x;
    int tx = tid & 31, ty = tid >> 5;  // 32x8
    int v0 = blockIdx.x * 32, k0 = blockIdx.y * 32;
#pragma unroll
    for (int i = 0; i < 4; ++i)
        tile[ty + i * 8][tx] = W[(size_t)(k0 + ty + i * 8) * V_ + v0 + tx];
    __syncthreads();
    if (tid < 128) {
        int vl = tid >> 2, lg = tid & 3;
        int v  = v0 + vl;
        float x[8];
#pragma unroll
        for (int j = 0; j < 8; ++j) x[j] = tile[lg * 8 + j][vl];
        int lo = 0, hi = 0;
        lo = __builtin_amdgcn_cvt_pk_fp8_f32(x[0], x[1], lo, false);
        lo = __builtin_amdgcn_cvt_pk_fp8_f32(x[2], x[3], lo, true);
        hi = __builtin_amdgcn_cvt_pk_fp8_f32(x[4], x[5], hi, false);
        hi = __builtin_amdgcn_cvt_pk_fp8_f32(x[6], x[7], hi, true);
        int tl = v >> 4, ln = v & 15, kt = k0 >> 5;
        *(int2*)(Wf + tl * 8192 + kt * 512 + (lg * 16 + ln) * 8) = make_int2(lo, hi);
    }
}

// ---- Kernel H: h = tanh(ep+pp) fp8, pre-swizzled, OUTPUT-LINEAR (coalesced writes) ---
__global__ __launch_bounds__(512) void hgen_kernel(const float* __restrict__ ep,
                                                   const float* __restrict__ pp,
                                                   unsigned char* __restrict__ hG) {
    int tid  = threadIdx.x;
    int tile = blockIdx.x;
    unsigned char* outb = hG + (size_t)tile * 32768;
#pragma unroll
    for (int i = 0; i < 4; ++i) {
        int g   = tid + i * 512;
        int row = g >> 5;
        int lin9 = (g & 31) * 16;
        unsigned swz = ((unsigned)(row & 15)) << 3;
        int k0   = lin9 ^ (int)(swz & ~8u);
        int swap = row & 1;
        int cell = tile * 64 + row;
        unsigned epRow = (unsigned)cell / 65u;
        int u = cell - (int)epRow * 65;
        int b = (int)(epRow >> 8);
        const float* epr = ep + (size_t)epRow * J_ + k0;
        const float* ppr = pp + (size_t)(b * UP1 + u) * J_ + k0;
        float t[16];
#pragma unroll
        for (int q = 0; q < 4; ++q) {
            float4 e = *(const float4*)(epr + q * 4);
            float4 p = *(const float4*)(ppr + q * 4);
            float xs[4] = {e.x + p.x, e.y + p.y, e.z + p.z, e.w + p.w};
#pragma unroll
            for (int j = 0; j < 4; ++j) {
                float e2 = __expf(2.f * xs[j]);
                t[q * 4 + j] = 1.f - 2.f / (e2 + 1.f);
            }
        }
        int a0 = 0, a1 = 0, b0 = 0, b1 = 0;
        a0 = __builtin_amdgcn_cvt_pk_fp8_f32(t[0], t[1], a0, false);
        a0 = __builtin_amdgcn_cvt_pk_fp8_f32(t[2], t[3], a0, true);
        a1 = __builtin_amdgcn_cvt_pk_fp8_f32(t[4], t[5], a1, false);
        a1 = __builtin_amdgcn_cvt_pk_fp8_f32(t[6], t[7], a1, true);
        b0 = __builtin_amdgcn_cvt_pk_fp8_f32(t[8], t[9], b0, false);
        b0 = __builtin_amdgcn_cvt_pk_fp8_f32(t[10], t[11], b0, true);
        b1 = __builtin_amdgcn_cvt_pk_fp8_f32(t[12], t[13], b1, false);
        b1 = __builtin_amdgcn_cvt_pk_fp8_f32(t[14], t[15], b1, true);
        int4 w = swap ? make_int4(b0, b1, a0, a1) : make_int4(a0, a1, b0, b1);
        *(int4*)(outb + g * 16) = w;
    }
}

// ---- Kernel B: fp8-K32 joint, reg staging, XCD-grouped, (256,3) known-good ----------
__global__ __launch_bounds__(256, 3) void joint_mfma(const unsigned char* __restrict__ hG,
                                                     const unsigned char* __restrict__ Wf,
                                                     const float* __restrict__ bout,
                                                     const int* __restrict__ labels,
                                                     const int* __restrict__ pblank,
                                                     float* __restrict__ Spart,
                                                     float* __restrict__ blp,
                                                     float* __restrict__ llp) {
    __shared__ __align__(16) unsigned char hB[64 * 512];
    __shared__ float ps[4][64];

    int tid  = threadIdx.x;
    int bx   = blockIdx.x;
    int tile = (bx >> 5) * 8 + (bx & 7);
    int bh   = (bx >> 3) & 3;
    int c0   = tile * 64;
    int wc = tid >> 6, lane = tid & 63;
    int lg = lane >> 4, ln = lane & 15;

    const long* wfbL = (const long*)Wf + (((bh << 4) + (wc << 2)) << 10) + lane;

    long bf[3][4];
    long af[2][4];

    // ---- stage: linear 32KB reg copy hG -> LDS, bf prologue overlapped ----
    {
        int4 v[8];
        const int4* g = (const int4*)(hG + (size_t)tile * 32768) + tid;
#pragma unroll
        for (int i = 0; i < 8; ++i) v[i] = g[i * 256];
#pragma unroll
        for (int ni = 0; ni < 4; ++ni) bf[0][ni] = wfbL[ni * 1024];
#pragma unroll
        for (int ni = 0; ni < 4; ++ni) bf[1][ni] = wfbL[ni * 1024 + 64];
#pragma unroll
        for (int i = 0; i < 8; ++i) ((int4*)hB)[tid + i * 256] = v[i];
    }
    __syncthreads();

    f32x4 acc[4][4] = {};
#pragma unroll
    for (int mi = 0; mi < 4; ++mi)
        af[0][mi] = *(const long*)(hB + hb8((unsigned)(mi * 16 + ln), (unsigned)(lg * 8)));

#pragma unroll
    for (int kt = 0; kt < 16; ++kt) {
        const int cur3 = kt % 3;
        const int pf3  = (kt + 2) % 3;
        const int cur  = kt & 1, nxt = cur ^ 1;
#pragma unroll
        for (int ni = 0; ni < 4; ++ni) {
            if (kt < 14) bf[pf3][ni] = wfbL[ni * 1024 + (kt + 2) * 64];
            __builtin_amdgcn_s_setprio(1);
#pragma unroll
            for (int mi = 0; mi < 4; ++mi)
                acc[mi][ni] = __builtin_amdgcn_mfma_f32_16x16x32_fp8_fp8(
                    af[cur][mi], bf[cur3][ni], acc[mi][ni], 0, 0, 0);
            __builtin_amdgcn_s_setprio(0);
            if (ni == 1 && kt < 15) {
#pragma unroll
                for (int mi = 0; mi < 4; ++mi) {
                    unsigned m  = (unsigned)(mi * 16 + ln);
                    unsigned cb = (unsigned)((kt + 1) * 32 + lg * 8);
                    af[nxt][mi] = *(const long*)(hB + hb8(m, cb));
                }
            }
        }
    }

    // ---- epilogue: bias, partial exp-sum over this quarter's 256 cols, raw gather ----
    float bo[4];
#pragma unroll
    for (int ni = 0; ni < 4; ++ni) bo[ni] = bout[(bh << 8) + (wc << 6) + (ni << 4) + ln];
#pragma unroll
    for (int mi = 0; mi < 4; ++mi)
#pragma unroll
        for (int ni = 0; ni < 4; ++ni)
#pragma unroll
            for (int r = 0; r < 4; ++r) acc[mi][ni][r] += bo[ni];

#pragma unroll
    for (int mi = 0; mi < 4; ++mi) {
#pragma unroll
        for (int r = 0; r < 4; ++r) {
            float s = 0.f;
#pragma unroll
            for (int ni = 0; ni < 4; ++ni) s += __expf(acc[mi][ni][r]);
            s += __shfl_xor(s, 1);
            s += __shfl_xor(s, 2);
            s += __shfl_xor(s, 4);
            s += __shfl_xor(s, 8);
            if (ln == 0) ps[wc][mi * 16 + lg * 4 + r] = s;
        }
    }
    __syncthreads();
    if (tid < 64) {
        float S = ps[0][tid] + ps[1][tid] + ps[2][tid] + ps[3][tid];
        Spart[(size_t)bh * NCELL + c0 + tid] = S;
    }

    int blank = *pblank;
#pragma unroll
    for (int mi = 0; mi < 4; ++mi) {
#pragma unroll
        for (int r = 0; r < 4; ++r) {
            int row  = mi * 16 + lg * 4 + r;
            int cell = c0 + row;
            unsigned epRow = (unsigned)cell / 65u;
            int u = cell - (int)epRow * 65;
            int b = (int)(epRow >> 8);
            int lab = (u < U_) ? labels[(b << 6) + u] : -1;
#pragma unroll
            for (int ni = 0; ni < 4; ++ni) {
                int col = (bh << 8) + (wc << 6) + (ni << 4) + ln;
                float lgt = acc[mi][ni][r];
                if (col == blank) blp[cell] = lgt;                            // raw
                if (col == lab)   llp[(size_t)(((int)epRow << 6) + u)] = lgt; // raw
            }
        }
    }
}

// ---- Pass 2: lse = log(S0+S1+S2+S3); subtract from raw blank/label logits ----
__global__ __launch_bounds__(256) void pass2_kernel(const float* __restrict__ Spart,
                                                    float* __restrict__ blp,
                                                    float* __restrict__ llp) {
    int idx = blockIdx.x * 256 + threadIdx.x;
    if (idx >= NCELL) return;
    float lse = __logf(Spart[idx] + Spart[NCELL + idx] +
                       Spart[2 * NCELL + idx] + Spart[3 * NCELL + idx]);
    blp[idx] -= lse;
    unsigned epRow = (unsigned)idx / 65u;
    int u = idx - (int)epRow * 65;
    if (u < U_) llp[(size_t)((epRow << 6) + u)] -= lse;
}

// ------- Kernel C: alpha scan. 8 blocks x 1 wave. LDS-staged, telescoped recursion. ---
// Precompute (parallel over t): D_t[u] = L_{t-1}[u] + bv_t[u] - L_t[u] (log2 domain),
// E_t = P63_{t-1} + bv64_t - P63_t. Serial state g[u] = M + log2(prefixS[u]);
// alpha_t[u] = L_{t-1}[u] + g[u]. Chain per t: add -> max-tree -> exp2 -> sum-tree -> log2.
__global__ __launch_bounds__(64) void scan_kernel(const float* __restrict__ blp,
                                                  const float* __restrict__ llp,
                                                  const int* __restrict__ enc_lens,
                                                  const int* __restrict__ label_lens,
                                                  float* __restrict__ lossBuf) {
    __shared__ float sD[T_ * U_];   // 64 KB
    __shared__ float sE[T_];
    __shared__ float sFin[4];       // [0]=L[ll] at el-1, [1]=term (K2 dom), [2]=P63 at el-1
    const float K2  = 1.4426950408889634f;
    const float LN2 = 0.6931471805599453f;
    int b    = blockIdx.x;
    int lane = threadIdx.x;
    int el = enc_lens[b];
    int ll = label_lens[b];
    const float* bb = blp + (size_t)b * T_ * UP1;
    const float* lb = llp + (size_t)b * T_ * U_;

    // ---- precompute pass: chunked 8-deep batched loads (latency amortized) ----
    float Lprev = 0.f, P63prev = 0.f;
    for (int t0 = 0; t0 < el; t0 += 8) {
        float bvv[8], lvv[8], b64v[8];
#pragma unroll
        for (int j = 0; j < 8; ++j) {
            int t = t0 + j;
            bool v = t < el;
            bvv[j]  = v ? bb[t * UP1 + lane] : 0.f;
            b64v[j] = v ? bb[t * UP1 + 64]   : 0.f;
            lvv[j]  = v ? lb[t * U_ + lane]  : 0.f;
        }
#pragma unroll
        for (int j = 0; j < 8; ++j) {
            int t = t0 + j;
            if (t >= el) break;                     // wave-uniform
            float P = wave_prefix_sum(lvv[j] * K2);
            float L = dpps<0x111, 0xf>(P);
            float P15 = rdlane(P, 15), P31 = rdlane(P, 31), P47 = rdlane(P, 47);
            if (lane == 0)  L = 0.f;
            if (lane == 16) L = P15;
            if (lane == 32) L = P31;
            if (lane == 48) L = P47;
            float P63 = rdlane(P, 63);
            float bvK = bvv[j] * K2;
            sD[t * U_ + lane] = Lprev + bvK - L;
            if (lane == 0) sE[t] = P63prev + b64v[j] * K2 - P63;
            if (t == el - 1) {
                if (ll < 64) {
                    if (lane == ll) { sFin[0] = L; sFin[1] = bvK; }
                } else if (lane == 0) {
                    sFin[1] = b64v[j] * K2;
                }
                if (lane == 0) sFin[2] = P63;
            }
            Lprev = L;
            P63prev = P63;
        }
    }
    __syncthreads();

    // ---- serial pass: pure-VALU chain, LDS 1-deep prefetch ----
    float g   = (lane == 0) ? 0.f : LOG0;
    float g64 = LOG0;
    float Dn = sD[lane];
    float En = sE[0];
    for (int t = 0; t < el; ++t) {
        float d = Dn, e0 = En;
        if (t + 1 < el) {
            Dn = sD[(t + 1) * U_ + lane];
            En = sE[t + 1];
        }
        float x   = g + d;
        float x64 = g64 + e0;
        float M = fmaxf(wave_max_all(x), x64);
        float ex = __builtin_amdgcn_exp2f(x - M);
        float S = wave_prefix_sum(ex);
        float S63 = rdlane(S, 63);
        g   = M + __builtin_amdgcn_logf(S);
        g64 = M + __builtin_amdgcn_logf(S63 + __builtin_amdgcn_exp2f(x64 - M));
    }

    float aU = (ll < 64) ? (sFin[0] + __shfl(g, ll)) : (sFin[2] + g64);
    if (lane == 0) lossBuf[b] = -(aU + sFin[1]) * LN2;
}

// ---- Finalize: mean of per-batch losses ----
__global__ __launch_bounds__(64) void finalize_kernel(const float* __restrict__ lossBuf,
                                                      float* __restrict__ out) {
    if (threadIdx.x == 0) {
        float s = 0.f;
        for (int i = 0; i < B_; ++i) s += lossBuf[i];
        out[0] = s / (float)B_;
    }
}

extern "C" void kernel_launch(void* const* d_in, const int* in_sizes, int n_in,
                              void* d_out, int out_size, void* d_ws, size_t ws_size,
                              hipStream_t stream) {
    (void)in_sizes; (void)n_in; (void)out_size; (void)ws_size;
    const float* enc        = (const float*)d_in[0];
    const float* pred       = (const float*)d_in[1];
    const float* W_enc      = (const float*)d_in[2];
    const float* W_pred     = (const float*)d_in[3];
    const float* b_joint    = (const float*)d_in[4];
    const float* W_out      = (const float*)d_in[5];
    const float* b_out      = (const float*)d_in[6];
    const int*   labels     = (const int*)d_in[7];
    const int*   enc_lens   = (const int*)d_in[8];
    const int*   label_lens = (const int*)d_in[9];
    const int*   blank_id   = (const int*)d_in[10];

    float* ep  = (float*)d_ws;                      // B*T*J   = 1,048,576 f
    float* pp  = ep  + (size_t)B_ * T_ * J_;        // B*65*J  =   266,240 f
    float* blp = pp  + (size_t)B_ * UP1 * J_;       // B*T*65  =   133,120 f
    float* llp = blp + (size_t)B_ * T_ * UP1;       // B*T*64  =   131,072 f
    unsigned char* Wf = (unsigned char*)(llp + (size_t)B_ * T_ * U_);  // 512KB frag fp8
    float* Spart = (float*)(Wf + (size_t)V_ * J_);  // 4 * NCELL f32
    unsigned char* hG = (unsigned char*)(Spart + (size_t)4 * NCELL);   // NCELL*512 fp8
    float* lossBuf = (float*)(hG + (size_t)NCELL * 512);               // B_ f32

    wt_kernel<<<dim3(V_ / 32, J_ / 32), dim3(256), 0, stream>>>(W_out, Wf);
    gemm_in<<<dim3((B_ * T_ + 31) / 32, J_ / 64), dim3(256), 0, stream>>>(
        enc, W_enc, b_joint, ep, B_ * T_);
    gemm_in<<<dim3((B_ * UP1 + 31) / 32, J_ / 64), dim3(256), 0, stream>>>(
        pred, W_pred, nullptr, pp, B_ * UP1);
    hgen_kernel<<<dim3(NCELL / 64), dim3(512), 0, stream>>>(ep, pp, hG);
    joint_mfma<<<dim3(NCELL / 64 * 4), dim3(256), 0, stream>>>(
        hG, Wf, b_out, labels, blank_id, Spart, blp, llp);
    pass2_kernel<<<dim3((NCELL + 255) / 256), dim3(256), 0, stream>>>(Spart, blp, llp);
    scan_kernel<<<dim3(B_), dim3(64), 0, stream>>>(blp, llp, enc_lens, label_lens,
                                                   lossBuf);
    finalize_kernel<<<dim3(1), dim3(64), 0, stream>>>(lossBuf, (float*)d_out);
}

// Round 17
// 317.782 us; speedup vs baseline: 1.2457x; 1.2457x over previous
//
#include <hip/hip_runtime.h>
#include <math.h>

#define B_   8
#define T_   256
#define U_   64
#define UP1  65
#define DE   640
#define J_   512
#define V_   1024
#define NCELL (B_ * T_ * UP1)
#define LOG0 -1e30f
#define NSEG 8
#define SEGLEN 32
#define MLD  66   // matrix column leading dim (65 rows + 1 pad)

typedef __attribute__((ext_vector_type(4))) float f32x4;

// ---------------- DPP wave64 scan/reduce helpers -------------------------------------
template<int CTRL, int RM>
__device__ __forceinline__ float dppz(float x) {
    return __builtin_bit_cast(float,
        __builtin_amdgcn_update_dpp(0, __builtin_bit_cast(int, x), CTRL, RM, 0xf, false));
}
template<int CTRL, int RM>
__device__ __forceinline__ float dpps(float x) {
    int xi = __builtin_bit_cast(int, x);
    return __builtin_bit_cast(float,
        __builtin_amdgcn_update_dpp(xi, xi, CTRL, RM, 0xf, false));
}
__device__ __forceinline__ float wave_prefix_sum(float v) {
    v += dppz<0x111, 0xf>(v);
    v += dppz<0x112, 0xf>(v);
    v += dppz<0x114, 0xf>(v);
    v += dppz<0x118, 0xf>(v);
    v += dppz<0x142, 0xa>(v);
    v += dppz<0x143, 0xc>(v);
    return v;
}
__device__ __forceinline__ float wave_max_all(float v) {
    v = fmaxf(v, dpps<0x111, 0xf>(v));
    v = fmaxf(v, dpps<0x112, 0xf>(v));
    v = fmaxf(v, dpps<0x114, 0xf>(v));
    v = fmaxf(v, dpps<0x118, 0xf>(v));
    v = fmaxf(v, dpps<0x142, 0xa>(v));
    v = fmaxf(v, dpps<0x143, 0xc>(v));
    return __builtin_bit_cast(float,
        __builtin_amdgcn_readlane(__builtin_bit_cast(int, v), 63));
}
__device__ __forceinline__ float rdlane(float v, int l) {
    return __builtin_bit_cast(float,
        __builtin_amdgcn_readlane(__builtin_bit_cast(int, v), l));
}

// LDS swizzle for fp8 hB: row m (512B rows), cb = column byte offset (8B granular).
__device__ __forceinline__ unsigned hb8(unsigned m, unsigned cb) {
    return m * 512u + (cb ^ ((m & 15u) << 3));
}

// ------- Kernel A: C[M x 512] = A[M x 640] * W[640 x 512] (+bias), 32x64 tiles --------
__global__ __launch_bounds__(256) void gemm_in(const float* __restrict__ A,
                                               const float* __restrict__ W,
                                               const float* __restrict__ bias,
                                               float* __restrict__ C, int M) {
    __shared__ float As[16][32];
    __shared__ float Bs[16][64];
    int tid  = threadIdx.x;
    int row0 = blockIdx.x * 32;
    int col0 = blockIdx.y * 64;
    int tx = tid & 15, ty = tid >> 4;
    float acc[2][4] = {};
    int ar  = tid >> 3;
    int ak2 = (tid & 7) * 2;
    int bkr = tid >> 4;
    int bcq = tid & 15;
    for (int k0 = 0; k0 < DE; k0 += 16) {
        float2 av = make_float2(0.f, 0.f);
        int arow = row0 + ar;
        if (arow < M) av = *(const float2*)&A[arow * DE + k0 + ak2];
        As[ak2][ar]     = av.x;
        As[ak2 + 1][ar] = av.y;
        *(float4*)&Bs[bkr][bcq * 4] = *(const float4*)&W[(k0 + bkr) * J_ + col0 + bcq * 4];
        __syncthreads();
#pragma unroll
        for (int k = 0; k < 16; ++k) {
            float a0 = As[k][ty * 2], a1 = As[k][ty * 2 + 1];
            float4 b4 = *(const float4*)&Bs[k][tx * 4];
            float b[4] = {b4.x, b4.y, b4.z, b4.w};
#pragma unroll
            for (int j = 0; j < 4; ++j) {
                acc[0][j] += a0 * b[j];
                acc[1][j] += a1 * b[j];
            }
        }
        __syncthreads();
    }
#pragma unroll
    for (int i = 0; i < 2; ++i) {
        int row = row0 + ty * 2 + i;
        if (row >= M) continue;
#pragma unroll
        for (int j = 0; j < 4; ++j) {
            int col = col0 + tx * 4 + j;
            float v = acc[i][j];
            if (bias) v += bias[col];
            C[row * J_ + col] = v;
        }
    }
}

// ---- Kernel W: W_out[512][1024] -> fragment-major fp8(e4m3) Wf (round-6 K32 layout) --
__global__ __launch_bounds__(256) void wt_kernel(const float* __restrict__ W,
                                                 unsigned char* __restrict__ Wf) {
    __shared__ float tile[32][33];
    int tid = threadIdx.x;
    int tx = tid & 31, ty = tid >> 5;  // 32x8
    int v0 = blockIdx.x * 32, k0 = blockIdx.y * 32;
#pragma unroll
    for (int i = 0; i < 4; ++i)
        tile[ty + i * 8][tx] = W[(size_t)(k0 + ty + i * 8) * V_ + v0 + tx];
    __syncthreads();
    if (tid < 128) {
        int vl = tid >> 2, lg = tid & 3;
        int v  = v0 + vl;
        float x[8];
#pragma unroll
        for (int j = 0; j < 8; ++j) x[j] = tile[lg * 8 + j][vl];
        int lo = 0, hi = 0;
        lo = __builtin_amdgcn_cvt_pk_fp8_f32(x[0], x[1], lo, false);
        lo = __builtin_amdgcn_cvt_pk_fp8_f32(x[2], x[3], lo, true);
        hi = __builtin_amdgcn_cvt_pk_fp8_f32(x[4], x[5], hi, false);
        hi = __builtin_amdgcn_cvt_pk_fp8_f32(x[6], x[7], hi, true);
        int tl = v >> 4, ln = v & 15, kt = k0 >> 5;
        *(int2*)(Wf + tl * 8192 + kt * 512 + (lg * 16 + ln) * 8) = make_int2(lo, hi);
    }
}

// ---- Kernel H: h = tanh(ep+pp) fp8, pre-swizzled, OUTPUT-LINEAR (coalesced writes) ---
__global__ __launch_bounds__(512) void hgen_kernel(const float* __restrict__ ep,
                                                   const float* __restrict__ pp,
                                                   unsigned char* __restrict__ hG) {
    int tid  = threadIdx.x;
    int tile = blockIdx.x;
    unsigned char* outb = hG + (size_t)tile * 32768;
#pragma unroll
    for (int i = 0; i < 4; ++i) {
        int g   = tid + i * 512;
        int row = g >> 5;
        int lin9 = (g & 31) * 16;
        unsigned swz = ((unsigned)(row & 15)) << 3;
        int k0   = lin9 ^ (int)(swz & ~8u);
        int swap = row & 1;
        int cell = tile * 64 + row;
        unsigned epRow = (unsigned)cell / 65u;
        int u = cell - (int)epRow * 65;
        int b = (int)(epRow >> 8);
        const float* epr = ep + (size_t)epRow * J_ + k0;
        const float* ppr = pp + (size_t)(b * UP1 + u) * J_ + k0;
        float t[16];
#pragma unroll
        for (int q = 0; q < 4; ++q) {
            float4 e = *(const float4*)(epr + q * 4);
            float4 p = *(const float4*)(ppr + q * 4);
            float xs[4] = {e.x + p.x, e.y + p.y, e.z + p.z, e.w + p.w};
#pragma unroll
            for (int j = 0; j < 4; ++j) {
                float e2 = __expf(2.f * xs[j]);
                t[q * 4 + j] = 1.f - 2.f / (e2 + 1.f);
            }
        }
        int a0 = 0, a1 = 0, b0 = 0, b1 = 0;
        a0 = __builtin_amdgcn_cvt_pk_fp8_f32(t[0], t[1], a0, false);
        a0 = __builtin_amdgcn_cvt_pk_fp8_f32(t[2], t[3], a0, true);
        a1 = __builtin_amdgcn_cvt_pk_fp8_f32(t[4], t[5], a1, false);
        a1 = __builtin_amdgcn_cvt_pk_fp8_f32(t[6], t[7], a1, true);
        b0 = __builtin_amdgcn_cvt_pk_fp8_f32(t[8], t[9], b0, false);
        b0 = __builtin_amdgcn_cvt_pk_fp8_f32(t[10], t[11], b0, true);
        b1 = __builtin_amdgcn_cvt_pk_fp8_f32(t[12], t[13], b1, false);
        b1 = __builtin_amdgcn_cvt_pk_fp8_f32(t[14], t[15], b1, true);
        int4 w = swap ? make_int4(b0, b1, a0, a1) : make_int4(a0, a1, b0, b1);
        *(int4*)(outb + g * 16) = w;
    }
}

// ---- Kernel B: fp8-K32 joint, reg staging, XCD-grouped, (256,3) known-good ----------
__global__ __launch_bounds__(256, 3) void joint_mfma(const unsigned char* __restrict__ hG,
                                                     const unsigned char* __restrict__ Wf,
                                                     const float* __restrict__ bout,
                                                     const int* __restrict__ labels,
                                                     const int* __restrict__ pblank,
                                                     float* __restrict__ Spart,
                                                     float* __restrict__ blp,
                                                     float* __restrict__ llp) {
    __shared__ __align__(16) unsigned char hB[64 * 512];
    __shared__ float ps[4][64];

    int tid  = threadIdx.x;
    int bx   = blockIdx.x;
    int tile = (bx >> 5) * 8 + (bx & 7);
    int bh   = (bx >> 3) & 3;
    int c0   = tile * 64;
    int wc = tid >> 6, lane = tid & 63;
    int lg = lane >> 4, ln = lane & 15;

    const long* wfbL = (const long*)Wf + (((bh << 4) + (wc << 2)) << 10) + lane;

    long bf[3][4];
    long af[2][4];

    // ---- stage: linear 32KB reg copy hG -> LDS, bf prologue overlapped ----
    {
        int4 v[8];
        const int4* g = (const int4*)(hG + (size_t)tile * 32768) + tid;
#pragma unroll
        for (int i = 0; i < 8; ++i) v[i] = g[i * 256];
#pragma unroll
        for (int ni = 0; ni < 4; ++ni) bf[0][ni] = wfbL[ni * 1024];
#pragma unroll
        for (int ni = 0; ni < 4; ++ni) bf[1][ni] = wfbL[ni * 1024 + 64];
#pragma unroll
        for (int i = 0; i < 8; ++i) ((int4*)hB)[tid + i * 256] = v[i];
    }
    __syncthreads();

    f32x4 acc[4][4] = {};
#pragma unroll
    for (int mi = 0; mi < 4; ++mi)
        af[0][mi] = *(const long*)(hB + hb8((unsigned)(mi * 16 + ln), (unsigned)(lg * 8)));

#pragma unroll
    for (int kt = 0; kt < 16; ++kt) {
        const int cur3 = kt % 3;
        const int pf3  = (kt + 2) % 3;
        const int cur  = kt & 1, nxt = cur ^ 1;
#pragma unroll
        for (int ni = 0; ni < 4; ++ni) {
            if (kt < 14) bf[pf3][ni] = wfbL[ni * 1024 + (kt + 2) * 64];
            __builtin_amdgcn_s_setprio(1);
#pragma unroll
            for (int mi = 0; mi < 4; ++mi)
                acc[mi][ni] = __builtin_amdgcn_mfma_f32_16x16x32_fp8_fp8(
                    af[cur][mi], bf[cur3][ni], acc[mi][ni], 0, 0, 0);
            __builtin_amdgcn_s_setprio(0);
            if (ni == 1 && kt < 15) {
#pragma unroll
                for (int mi = 0; mi < 4; ++mi) {
                    unsigned m  = (unsigned)(mi * 16 + ln);
                    unsigned cb = (unsigned)((kt + 1) * 32 + lg * 8);
                    af[nxt][mi] = *(const long*)(hB + hb8(m, cb));
                }
            }
        }
    }

    // ---- epilogue: bias, partial exp-sum over this quarter's 256 cols, raw gather ----
    float bo[4];
#pragma unroll
    for (int ni = 0; ni < 4; ++ni) bo[ni] = bout[(bh << 8) + (wc << 6) + (ni << 4) + ln];
#pragma unroll
    for (int mi = 0; mi < 4; ++mi)
#pragma unroll
        for (int ni = 0; ni < 4; ++ni)
#pragma unroll
            for (int r = 0; r < 4; ++r) acc[mi][ni][r] += bo[ni];

#pragma unroll
    for (int mi = 0; mi < 4; ++mi) {
#pragma unroll
        for (int r = 0; r < 4; ++r) {
            float s = 0.f;
#pragma unroll
            for (int ni = 0; ni < 4; ++ni) s += __expf(acc[mi][ni][r]);
            s += __shfl_xor(s, 1);
            s += __shfl_xor(s, 2);
            s += __shfl_xor(s, 4);
            s += __shfl_xor(s, 8);
            if (ln == 0) ps[wc][mi * 16 + lg * 4 + r] = s;
        }
    }
    __syncthreads();
    if (tid < 64) {
        float S = ps[0][tid] + ps[1][tid] + ps[2][tid] + ps[3][tid];
        Spart[(size_t)bh * NCELL + c0 + tid] = S;
    }

    int blank = *pblank;
#pragma unroll
    for (int mi = 0; mi < 4; ++mi) {
#pragma unroll
        for (int r = 0; r < 4; ++r) {
            int row  = mi * 16 + lg * 4 + r;
            int cell = c0 + row;
            unsigned epRow = (unsigned)cell / 65u;
            int u = cell - (int)epRow * 65;
            int b = (int)(epRow >> 8);
            int lab = (u < U_) ? labels[(b << 6) + u] : -1;
#pragma unroll
            for (int ni = 0; ni < 4; ++ni) {
                int col = (bh << 8) + (wc << 6) + (ni << 4) + ln;
                float lgt = acc[mi][ni][r];
                if (col == blank) blp[cell] = lgt;                            // raw
                if (col == lab)   llp[(size_t)(((int)epRow << 6) + u)] = lgt; // raw
            }
        }
    }
}

// ---- Pass 2: lse = log(S0+S1+S2+S3); subtract from raw blank/label logits ----
__global__ __launch_bounds__(256) void pass2_kernel(const float* __restrict__ Spart,
                                                    float* __restrict__ blp,
                                                    float* __restrict__ llp) {
    int idx = blockIdx.x * 256 + threadIdx.x;
    if (idx >= NCELL) return;
    float lse = __logf(Spart[idx] + Spart[NCELL + idx] +
                       Spart[2 * NCELL + idx] + Spart[3 * NCELL + idx]);
    blp[idx] -= lse;
    unsigned epRow = (unsigned)idx / 65u;
    int u = idx - (int)epRow * 65;
    if (u < U_) llp[(size_t)((epRow << 6) + u)] -= lse;
}

// ------- Kernel S1: segment-operator build. Block = (b, seg, basis v); 1 wave. --------
// Runs the verified scan step for t in [seg*32, min(seg*32+32, el)) from alpha = e_v.
// Stores column v of the 65x65 segment matrix (clamped to >= LOG0).
__global__ __launch_bounds__(64) void segscan_kernel(const float* __restrict__ blp,
                                                     const float* __restrict__ llp,
                                                     const int* __restrict__ enc_lens,
                                                     float* __restrict__ Mbuf) {
    const float K2 = 1.4426950408889634f;
    int idx  = blockIdx.x;
    int v    = idx % 65;
    int seg  = (idx / 65) % NSEG;
    int b    = idx / (65 * NSEG);
    int lane = threadIdx.x;
    int el   = enc_lens[b];
    int t0   = seg * SEGLEN;
    if (t0 >= el) return;
    int t1 = min(t0 + SEGLEN, el);
    const float* bb = blp + (size_t)b * T_ * UP1;
    const float* lb = llp + (size_t)b * T_ * U_;

    float alpha   = (lane == v) ? 0.f : LOG0;
    float alpha64 = (v == 64) ? 0.f : LOG0;

    for (int t = t0; t < t1; ++t) {
        float bv   = bb[t * UP1 + lane] * K2;
        float bv64 = bb[t * UP1 + 64] * K2;
        float lv   = lb[t * U_ + lane] * K2;
        float P = wave_prefix_sum(lv);
        float L = dpps<0x111, 0xf>(P);
        float P15 = rdlane(P, 15), P31 = rdlane(P, 31), P47 = rdlane(P, 47);
        if (lane == 0)  L = 0.f;
        if (lane == 16) L = P15;
        if (lane == 32) L = P31;
        if (lane == 48) L = P47;
        float P63 = rdlane(P, 63);
        float x   = alpha + bv - L;
        float x64 = alpha64 + bv64 - P63;
        float M = fmaxf(wave_max_all(x), x64);
        float S = wave_prefix_sum(__builtin_amdgcn_exp2f(x - M));
        float S63 = rdlane(S, 63);
        alpha   = L + M + __builtin_amdgcn_logf(S);
        alpha64 = P63 + M +
                  __builtin_amdgcn_logf(S63 + __builtin_amdgcn_exp2f(x64 - M));
    }

    float* col = Mbuf + ((size_t)((b * NSEG + seg) * 65 + v)) * MLD;
    col[lane] = fmaxf(alpha, LOG0);
    if (lane == 0) col[64] = fmaxf(alpha64, LOG0);
}

// ------- Kernel S2: apply segment operators sequentially. 1 block/batch, 1 wave. ------
// x <- M_seg (semiring-matvec) x, for active segments; then loss.
__global__ __launch_bounds__(64) void apply_kernel(const float* __restrict__ Mbuf,
                                                   const float* __restrict__ blp,
                                                   const int* __restrict__ enc_lens,
                                                   const int* __restrict__ label_lens,
                                                   float* __restrict__ lossBuf) {
    __shared__ float Ml[65 * MLD];
    __shared__ float xv[66];
    const float K2  = 1.4426950408889634f;
    const float LN2 = 0.6931471805599453f;
    int b    = blockIdx.x;
    int lane = threadIdx.x;
    int el = enc_lens[b];
    int ll = label_lens[b];

    xv[lane] = (lane == 0) ? 0.f : LOG0;
    if (lane == 0) xv[64] = LOG0;
    __syncthreads();

    for (int seg = 0; seg < NSEG; ++seg) {
        if (seg * SEGLEN >= el) break;
        const float* src = Mbuf + (size_t)((b * NSEG + seg) * 65) * MLD;
        for (int i = lane; i < 65 * MLD; i += 64) Ml[i] = src[i];
        __syncthreads();
        // rows u = lane (0..63): y[u] = logsum_v(M[u][v] + x[v]), M[u][v] = Ml[v*MLD+u]
        float m = LOG0;
#pragma unroll 5
        for (int vv = 0; vv < 65; ++vv) m = fmaxf(m, Ml[vv * MLD + lane] + xv[vv]);
        m = fmaxf(m, LOG0);
        float s = 0.f;
#pragma unroll 5
        for (int vv = 0; vv < 65; ++vv)
            s += __builtin_amdgcn_exp2f(Ml[vv * MLD + lane] + xv[vv] - m);
        float y = fmaxf(m + __builtin_amdgcn_logf(s), LOG0);
        // row 64: lane-parallel over v (lane = v), plus v=64 term
        float t64  = xv[lane] + Ml[lane * MLD + 64];
        float t64b = xv[64] + Ml[64 * MLD + 64];
        float m64 = fmaxf(fmaxf(wave_max_all(t64), t64b), LOG0);
        float s64 = rdlane(wave_prefix_sum(__builtin_amdgcn_exp2f(t64 - m64)), 63);
        s64 += __builtin_amdgcn_exp2f(t64b - m64);
        float y64 = fmaxf(m64 + __builtin_amdgcn_logf(s64), LOG0);
        __syncthreads();
        xv[lane] = y;
        if (lane == 0) xv[64] = y64;
        __syncthreads();
    }

    if (lane == 0) {
        float aU = (ll < 64) ? xv[ll] : xv[64];
        float term = blp[(size_t)b * T_ * UP1 + (el - 1) * UP1 + ll] * K2;
        lossBuf[b] = -(aU + term) * LN2;
    }
}

// ---- Finalize: mean of per-batch losses ----
__global__ __launch_bounds__(64) void finalize_kernel(const float* __restrict__ lossBuf,
                                                      float* __restrict__ out) {
    if (threadIdx.x == 0) {
        float s = 0.f;
        for (int i = 0; i < B_; ++i) s += lossBuf[i];
        out[0] = s / (float)B_;
    }
}

extern "C" void kernel_launch(void* const* d_in, const int* in_sizes, int n_in,
                              void* d_out, int out_size, void* d_ws, size_t ws_size,
                              hipStream_t stream) {
    (void)in_sizes; (void)n_in; (void)out_size; (void)ws_size;
    const float* enc        = (const float*)d_in[0];
    const float* pred       = (const float*)d_in[1];
    const float* W_enc      = (const float*)d_in[2];
    const float* W_pred     = (const float*)d_in[3];
    const float* b_joint    = (const float*)d_in[4];
    const float* W_out      = (const float*)d_in[5];
    const float* b_out      = (const float*)d_in[6];
    const int*   labels     = (const int*)d_in[7];
    const int*   enc_lens   = (const int*)d_in[8];
    const int*   label_lens = (const int*)d_in[9];
    const int*   blank_id   = (const int*)d_in[10];

    float* ep  = (float*)d_ws;                      // B*T*J   = 1,048,576 f
    float* pp  = ep  + (size_t)B_ * T_ * J_;        // B*65*J  =   266,240 f
    float* blp = pp  + (size_t)B_ * UP1 * J_;       // B*T*65  =   133,120 f
    float* llp = blp + (size_t)B_ * T_ * UP1;       // B*T*64  =   131,072 f
    unsigned char* Wf = (unsigned char*)(llp + (size_t)B_ * T_ * U_);  // 512KB frag fp8
    float* Spart = (float*)(Wf + (size_t)V_ * J_);  // 4 * NCELL f32
    unsigned char* hG = (unsigned char*)(Spart + (size_t)4 * NCELL);   // NCELL*512 fp8
    float* lossBuf = (float*)(hG + (size_t)NCELL * 512);               // B_ f32
    float* Mbuf    = lossBuf + 64;                  // B_*8*65*66 f32 = 1.1 MB

    wt_kernel<<<dim3(V_ / 32, J_ / 32), dim3(256), 0, stream>>>(W_out, Wf);
    gemm_in<<<dim3((B_ * T_ + 31) / 32, J_ / 64), dim3(256), 0, stream>>>(
        enc, W_enc, b_joint, ep, B_ * T_);
    gemm_in<<<dim3((B_ * UP1 + 31) / 32, J_ / 64), dim3(256), 0, stream>>>(
        pred, W_pred, nullptr, pp, B_ * UP1);
    hgen_kernel<<<dim3(NCELL / 64), dim3(512), 0, stream>>>(ep, pp, hG);
    joint_mfma<<<dim3(NCELL / 64 * 4), dim3(256), 0, stream>>>(
        hG, Wf, b_out, labels, blank_id, Spart, blp, llp);
    pass2_kernel<<<dim3((NCELL + 255) / 256), dim3(256), 0, stream>>>(Spart, blp, llp);
    segscan_kernel<<<dim3(B_ * NSEG * 65), dim3(64), 0, stream>>>(blp, llp, enc_lens,
                                                                  Mbuf);
    apply_kernel<<<dim3(B_), dim3(64), 0, stream>>>(Mbuf, blp, enc_lens, label_lens,
                                                    lossBuf);
    finalize_kernel<<<dim3(1), dim3(64), 0, stream>>>(lossBuf, (float*)d_out);
}

// Round 18
// 314.292 us; speedup vs baseline: 1.2595x; 1.0111x over previous
//
#include <hip/hip_runtime.h>
#include <math.h>

#define B_   8
#define T_   256
#define U_   64
#define UP1  65
#define DE   640
#define J_   512
#define V_   1024
#define NCELL (B_ * T_ * UP1)
#define LOG0 -1e30f
#define NSEG 8
#define SEGLEN 32
#define MLD  66   // matrix column leading dim (65 rows + 1 pad)

typedef __attribute__((ext_vector_type(4))) float f32x4;

// ---------------- DPP wave64 scan/reduce helpers -------------------------------------
template<int CTRL, int RM>
__device__ __forceinline__ float dppz(float x) {
    return __builtin_bit_cast(float,
        __builtin_amdgcn_update_dpp(0, __builtin_bit_cast(int, x), CTRL, RM, 0xf, false));
}
template<int CTRL, int RM>
__device__ __forceinline__ float dpps(float x) {
    int xi = __builtin_bit_cast(int, x);
    return __builtin_bit_cast(float,
        __builtin_amdgcn_update_dpp(xi, xi, CTRL, RM, 0xf, false));
}
__device__ __forceinline__ float wave_prefix_sum(float v) {
    v += dppz<0x111, 0xf>(v);
    v += dppz<0x112, 0xf>(v);
    v += dppz<0x114, 0xf>(v);
    v += dppz<0x118, 0xf>(v);
    v += dppz<0x142, 0xa>(v);
    v += dppz<0x143, 0xc>(v);
    return v;
}
__device__ __forceinline__ float wave_max_all(float v) {
    v = fmaxf(v, dpps<0x111, 0xf>(v));
    v = fmaxf(v, dpps<0x112, 0xf>(v));
    v = fmaxf(v, dpps<0x114, 0xf>(v));
    v = fmaxf(v, dpps<0x118, 0xf>(v));
    v = fmaxf(v, dpps<0x142, 0xa>(v));
    v = fmaxf(v, dpps<0x143, 0xc>(v));
    return __builtin_bit_cast(float,
        __builtin_amdgcn_readlane(__builtin_bit_cast(int, v), 63));
}
__device__ __forceinline__ float rdlane(float v, int l) {
    return __builtin_bit_cast(float,
        __builtin_amdgcn_readlane(__builtin_bit_cast(int, v), l));
}

// LDS swizzle for fp8 hB: row m (512B rows), cb = column byte offset (8B granular).
__device__ __forceinline__ unsigned hb8(unsigned m, unsigned cb) {
    return m * 512u + (cb ^ ((m & 15u) << 3));
}

// ------- Kernel A: C[M x 512] = A[M x 640] * W[640 x 512] (+bias), 32x64 tiles --------
__global__ __launch_bounds__(256) void gemm_in(const float* __restrict__ A,
                                               const float* __restrict__ W,
                                               const float* __restrict__ bias,
                                               float* __restrict__ C, int M) {
    __shared__ float As[16][32];
    __shared__ float Bs[16][64];
    int tid  = threadIdx.x;
    int row0 = blockIdx.x * 32;
    int col0 = blockIdx.y * 64;
    int tx = tid & 15, ty = tid >> 4;
    float acc[2][4] = {};
    int ar  = tid >> 3;
    int ak2 = (tid & 7) * 2;
    int bkr = tid >> 4;
    int bcq = tid & 15;
    for (int k0 = 0; k0 < DE; k0 += 16) {
        float2 av = make_float2(0.f, 0.f);
        int arow = row0 + ar;
        if (arow < M) av = *(const float2*)&A[arow * DE + k0 + ak2];
        As[ak2][ar]     = av.x;
        As[ak2 + 1][ar] = av.y;
        *(float4*)&Bs[bkr][bcq * 4] = *(const float4*)&W[(k0 + bkr) * J_ + col0 + bcq * 4];
        __syncthreads();
#pragma unroll
        for (int k = 0; k < 16; ++k) {
            float a0 = As[k][ty * 2], a1 = As[k][ty * 2 + 1];
            float4 b4 = *(const float4*)&Bs[k][tx * 4];
            float b[4] = {b4.x, b4.y, b4.z, b4.w};
#pragma unroll
            for (int j = 0; j < 4; ++j) {
                acc[0][j] += a0 * b[j];
                acc[1][j] += a1 * b[j];
            }
        }
        __syncthreads();
    }
#pragma unroll
    for (int i = 0; i < 2; ++i) {
        int row = row0 + ty * 2 + i;
        if (row >= M) continue;
#pragma unroll
        for (int j = 0; j < 4; ++j) {
            int col = col0 + tx * 4 + j;
            float v = acc[i][j];
            if (bias) v += bias[col];
            C[row * J_ + col] = v;
        }
    }
}

// ---- Kernel W: W_out[512][1024] -> fragment-major fp8(e4m3) Wf (round-6 K32 layout) --
__global__ __launch_bounds__(256) void wt_kernel(const float* __restrict__ W,
                                                 unsigned char* __restrict__ Wf) {
    __shared__ float tile[32][33];
    int tid = threadIdx.x;
    int tx = tid & 31, ty = tid >> 5;  // 32x8
    int v0 = blockIdx.x * 32, k0 = blockIdx.y * 32;
#pragma unroll
    for (int i = 0; i < 4; ++i)
        tile[ty + i * 8][tx] = W[(size_t)(k0 + ty + i * 8) * V_ + v0 + tx];
    __syncthreads();
    if (tid < 128) {
        int vl = tid >> 2, lg = tid & 3;
        int v  = v0 + vl;
        float x[8];
#pragma unroll
        for (int j = 0; j < 8; ++j) x[j] = tile[lg * 8 + j][vl];
        int lo = 0, hi = 0;
        lo = __builtin_amdgcn_cvt_pk_fp8_f32(x[0], x[1], lo, false);
        lo = __builtin_amdgcn_cvt_pk_fp8_f32(x[2], x[3], lo, true);
        hi = __builtin_amdgcn_cvt_pk_fp8_f32(x[4], x[5], hi, false);
        hi = __builtin_amdgcn_cvt_pk_fp8_f32(x[6], x[7], hi, true);
        int tl = v >> 4, ln = v & 15, kt = k0 >> 5;
        *(int2*)(Wf + tl * 8192 + kt * 512 + (lg * 16 + ln) * 8) = make_int2(lo, hi);
    }
}

// ---- Kernel H: h = tanh(ep+pp) fp8, pre-swizzled, OUTPUT-LINEAR (coalesced writes) ---
__global__ __launch_bounds__(512) void hgen_kernel(const float* __restrict__ ep,
                                                   const float* __restrict__ pp,
                                                   unsigned char* __restrict__ hG) {
    int tid  = threadIdx.x;
    int tile = blockIdx.x;
    unsigned char* outb = hG + (size_t)tile * 32768;
#pragma unroll
    for (int i = 0; i < 4; ++i) {
        int g   = tid + i * 512;
        int row = g >> 5;
        int lin9 = (g & 31) * 16;
        unsigned swz = ((unsigned)(row & 15)) << 3;
        int k0   = lin9 ^ (int)(swz & ~8u);
        int swap = row & 1;
        int cell = tile * 64 + row;
        unsigned epRow = (unsigned)cell / 65u;
        int u = cell - (int)epRow * 65;
        int b = (int)(epRow >> 8);
        const float* epr = ep + (size_t)epRow * J_ + k0;
        const float* ppr = pp + (size_t)(b * UP1 + u) * J_ + k0;
        float t[16];
#pragma unroll
        for (int q = 0; q < 4; ++q) {
            float4 e = *(const float4*)(epr + q * 4);
            float4 p = *(const float4*)(ppr + q * 4);
            float xs[4] = {e.x + p.x, e.y + p.y, e.z + p.z, e.w + p.w};
#pragma unroll
            for (int j = 0; j < 4; ++j) {
                float e2 = __expf(2.f * xs[j]);
                t[q * 4 + j] = 1.f - 2.f / (e2 + 1.f);
            }
        }
        int a0 = 0, a1 = 0, b0 = 0, b1 = 0;
        a0 = __builtin_amdgcn_cvt_pk_fp8_f32(t[0], t[1], a0, false);
        a0 = __builtin_amdgcn_cvt_pk_fp8_f32(t[2], t[3], a0, true);
        a1 = __builtin_amdgcn_cvt_pk_fp8_f32(t[4], t[5], a1, false);
        a1 = __builtin_amdgcn_cvt_pk_fp8_f32(t[6], t[7], a1, true);
        b0 = __builtin_amdgcn_cvt_pk_fp8_f32(t[8], t[9], b0, false);
        b0 = __builtin_amdgcn_cvt_pk_fp8_f32(t[10], t[11], b0, true);
        b1 = __builtin_amdgcn_cvt_pk_fp8_f32(t[12], t[13], b1, false);
        b1 = __builtin_amdgcn_cvt_pk_fp8_f32(t[14], t[15], b1, true);
        int4 w = swap ? make_int4(b0, b1, a0, a1) : make_int4(a0, a1, b0, b1);
        *(int4*)(outb + g * 16) = w;
    }
}

// ---- Kernel B: fp8-K32 joint, reg staging, XCD-grouped, (256,3) known-good ----------
__global__ __launch_bounds__(256, 3) void joint_mfma(const unsigned char* __restrict__ hG,
                                                     const unsigned char* __restrict__ Wf,
                                                     const float* __restrict__ bout,
                                                     const int* __restrict__ labels,
                                                     const int* __restrict__ pblank,
                                                     float* __restrict__ Spart,
                                                     float* __restrict__ blp,
                                                     float* __restrict__ llp) {
    __shared__ __align__(16) unsigned char hB[64 * 512];
    __shared__ float ps[4][64];

    int tid  = threadIdx.x;
    int bx   = blockIdx.x;
    int tile = (bx >> 5) * 8 + (bx & 7);
    int bh   = (bx >> 3) & 3;
    int c0   = tile * 64;
    int wc = tid >> 6, lane = tid & 63;
    int lg = lane >> 4, ln = lane & 15;

    const long* wfbL = (const long*)Wf + (((bh << 4) + (wc << 2)) << 10) + lane;

    long bf[3][4];
    long af[2][4];

    // ---- stage: linear 32KB reg copy hG -> LDS, bf prologue overlapped ----
    {
        int4 v[8];
        const int4* g = (const int4*)(hG + (size_t)tile * 32768) + tid;
#pragma unroll
        for (int i = 0; i < 8; ++i) v[i] = g[i * 256];
#pragma unroll
        for (int ni = 0; ni < 4; ++ni) bf[0][ni] = wfbL[ni * 1024];
#pragma unroll
        for (int ni = 0; ni < 4; ++ni) bf[1][ni] = wfbL[ni * 1024 + 64];
#pragma unroll
        for (int i = 0; i < 8; ++i) ((int4*)hB)[tid + i * 256] = v[i];
    }
    __syncthreads();

    f32x4 acc[4][4] = {};
#pragma unroll
    for (int mi = 0; mi < 4; ++mi)
        af[0][mi] = *(const long*)(hB + hb8((unsigned)(mi * 16 + ln), (unsigned)(lg * 8)));

#pragma unroll
    for (int kt = 0; kt < 16; ++kt) {
        const int cur3 = kt % 3;
        const int pf3  = (kt + 2) % 3;
        const int cur  = kt & 1, nxt = cur ^ 1;
#pragma unroll
        for (int ni = 0; ni < 4; ++ni) {
            if (kt < 14) bf[pf3][ni] = wfbL[ni * 1024 + (kt + 2) * 64];
            __builtin_amdgcn_s_setprio(1);
#pragma unroll
            for (int mi = 0; mi < 4; ++mi)
                acc[mi][ni] = __builtin_amdgcn_mfma_f32_16x16x32_fp8_fp8(
                    af[cur][mi], bf[cur3][ni], acc[mi][ni], 0, 0, 0);
            __builtin_amdgcn_s_setprio(0);
            if (ni == 1 && kt < 15) {
#pragma unroll
                for (int mi = 0; mi < 4; ++mi) {
                    unsigned m  = (unsigned)(mi * 16 + ln);
                    unsigned cb = (unsigned)((kt + 1) * 32 + lg * 8);
                    af[nxt][mi] = *(const long*)(hB + hb8(m, cb));
                }
            }
        }
    }

    // ---- epilogue: bias, partial exp-sum over this quarter's 256 cols, raw gather ----
    float bo[4];
#pragma unroll
    for (int ni = 0; ni < 4; ++ni) bo[ni] = bout[(bh << 8) + (wc << 6) + (ni << 4) + ln];
#pragma unroll
    for (int mi = 0; mi < 4; ++mi)
#pragma unroll
        for (int ni = 0; ni < 4; ++ni)
#pragma unroll
            for (int r = 0; r < 4; ++r) acc[mi][ni][r] += bo[ni];

#pragma unroll
    for (int mi = 0; mi < 4; ++mi) {
#pragma unroll
        for (int r = 0; r < 4; ++r) {
            float s = 0.f;
#pragma unroll
            for (int ni = 0; ni < 4; ++ni) s += __expf(acc[mi][ni][r]);
            s += __shfl_xor(s, 1);
            s += __shfl_xor(s, 2);
            s += __shfl_xor(s, 4);
            s += __shfl_xor(s, 8);
            if (ln == 0) ps[wc][mi * 16 + lg * 4 + r] = s;
        }
    }
    __syncthreads();
    if (tid < 64) {
        float S = ps[0][tid] + ps[1][tid] + ps[2][tid] + ps[3][tid];
        Spart[(size_t)bh * NCELL + c0 + tid] = S;
    }

    int blank = *pblank;
#pragma unroll
    for (int mi = 0; mi < 4; ++mi) {
#pragma unroll
        for (int r = 0; r < 4; ++r) {
            int row  = mi * 16 + lg * 4 + r;
            int cell = c0 + row;
            unsigned epRow = (unsigned)cell / 65u;
            int u = cell - (int)epRow * 65;
            int b = (int)(epRow >> 8);
            int lab = (u < U_) ? labels[(b << 6) + u] : -1;
#pragma unroll
            for (int ni = 0; ni < 4; ++ni) {
                int col = (bh << 8) + (wc << 6) + (ni << 4) + ln;
                float lgt = acc[mi][ni][r];
                if (col == blank) blp[cell] = lgt;                            // raw
                if (col == lab)   llp[(size_t)(((int)epRow << 6) + u)] = lgt; // raw
            }
        }
    }
}

// ---- Pass 2: lse = log(S0+S1+S2+S3); subtract from raw blank/label logits ----
__global__ __launch_bounds__(256) void pass2_kernel(const float* __restrict__ Spart,
                                                    float* __restrict__ blp,
                                                    float* __restrict__ llp) {
    int idx = blockIdx.x * 256 + threadIdx.x;
    if (idx >= NCELL) return;
    float lse = __logf(Spart[idx] + Spart[NCELL + idx] +
                       Spart[2 * NCELL + idx] + Spart[3 * NCELL + idx]);
    blp[idx] -= lse;
    unsigned epRow = (unsigned)idx / 65u;
    int u = idx - (int)epRow * 65;
    if (u < U_) llp[(size_t)((epRow << 6) + u)] -= lse;
}

// ------- Kernel S1: segment-operator build. Block = (b, seg, basis v); 1 wave. --------
// R18: batch-preload the segment's data into registers (static indices, full unroll)
// BEFORE the serial DPP chain -- load latency off the critical path (R15/R17 lesson).
__global__ __launch_bounds__(64) void segscan_kernel(const float* __restrict__ blp,
                                                     const float* __restrict__ llp,
                                                     const int* __restrict__ enc_lens,
                                                     float* __restrict__ Mbuf) {
    const float K2 = 1.4426950408889634f;
    int idx  = blockIdx.x;
    int v    = idx % 65;
    int seg  = (idx / 65) % NSEG;
    int b    = idx / (65 * NSEG);
    int lane = threadIdx.x;
    int el   = enc_lens[b];
    int t0   = seg * SEGLEN;
    if (t0 >= el) return;
    const float* bb = blp + (size_t)b * T_ * UP1;
    const float* lb = llp + (size_t)b * T_ * U_;

    // ---- batch preload: 96 independent L2 loads, fully pipelined ----
    float bvK[SEGLEN], lvK[SEGLEN], b64K[SEGLEN];
#pragma unroll
    for (int j = 0; j < SEGLEN; ++j) {
        int t  = t0 + j;
        int tc = (t < el) ? t : (el - 1);      // clamp: in-bounds, value unused if t>=el
        bvK[j]  = bb[tc * UP1 + lane] * K2;
        b64K[j] = bb[tc * UP1 + 64] * K2;
        lvK[j]  = lb[tc * U_ + lane] * K2;
    }

    float alpha   = (lane == v) ? 0.f : LOG0;
    float alpha64 = (v == 64) ? 0.f : LOG0;

#pragma unroll
    for (int j = 0; j < SEGLEN; ++j) {
        if (t0 + j < el) {                      // wave-uniform guard
            float P = wave_prefix_sum(lvK[j]);
            float L = dpps<0x111, 0xf>(P);
            float P15 = rdlane(P, 15), P31 = rdlane(P, 31), P47 = rdlane(P, 47);
            if (lane == 0)  L = 0.f;
            if (lane == 16) L = P15;
            if (lane == 32) L = P31;
            if (lane == 48) L = P47;
            float P63 = rdlane(P, 63);
            float x   = alpha + bvK[j] - L;
            float x64 = alpha64 + b64K[j] - P63;
            float M = fmaxf(wave_max_all(x), x64);
            float S = wave_prefix_sum(__builtin_amdgcn_exp2f(x - M));
            float S63 = rdlane(S, 63);
            alpha   = L + M + __builtin_amdgcn_logf(S);
            alpha64 = P63 + M +
                      __builtin_amdgcn_logf(S63 + __builtin_amdgcn_exp2f(x64 - M));
        }
    }

    float* col = Mbuf + ((size_t)((b * NSEG + seg) * 65 + v)) * MLD;
    col[lane] = fmaxf(alpha, LOG0);
    if (lane == 0) col[64] = fmaxf(alpha64, LOG0);
}

// ------- Kernel S2: apply segment operators sequentially. 1 block/batch, 1 wave. ------
__global__ __launch_bounds__(64) void apply_kernel(const float* __restrict__ Mbuf,
                                                   const float* __restrict__ blp,
                                                   const int* __restrict__ enc_lens,
                                                   const int* __restrict__ label_lens,
                                                   float* __restrict__ lossBuf) {
    __shared__ float Ml[65 * MLD];
    __shared__ float xv[66];
    const float K2  = 1.4426950408889634f;
    const float LN2 = 0.6931471805599453f;
    int b    = blockIdx.x;
    int lane = threadIdx.x;
    int el = enc_lens[b];
    int ll = label_lens[b];

    xv[lane] = (lane == 0) ? 0.f : LOG0;
    if (lane == 0) xv[64] = LOG0;
    __syncthreads();

    for (int seg = 0; seg < NSEG; ++seg) {
        if (seg * SEGLEN >= el) break;
        const float* src = Mbuf + (size_t)((b * NSEG + seg) * 65) * MLD;
        for (int i = lane; i < 65 * MLD; i += 64) Ml[i] = src[i];
        __syncthreads();
        float m = LOG0;
#pragma unroll 5
        for (int vv = 0; vv < 65; ++vv) m = fmaxf(m, Ml[vv * MLD + lane] + xv[vv]);
        m = fmaxf(m, LOG0);
        float s = 0.f;
#pragma unroll 5
        for (int vv = 0; vv < 65; ++vv)
            s += __builtin_amdgcn_exp2f(Ml[vv * MLD + lane] + xv[vv] - m);
        float y = fmaxf(m + __builtin_amdgcn_logf(s), LOG0);
        float t64  = xv[lane] + Ml[lane * MLD + 64];
        float t64b = xv[64] + Ml[64 * MLD + 64];
        float m64 = fmaxf(fmaxf(wave_max_all(t64), t64b), LOG0);
        float s64 = rdlane(wave_prefix_sum(__builtin_amdgcn_exp2f(t64 - m64)), 63);
        s64 += __builtin_amdgcn_exp2f(t64b - m64);
        float y64 = fmaxf(m64 + __builtin_amdgcn_logf(s64), LOG0);
        __syncthreads();
        xv[lane] = y;
        if (lane == 0) xv[64] = y64;
        __syncthreads();
    }

    if (lane == 0) {
        float aU = (ll < 64) ? xv[ll] : xv[64];
        float term = blp[(size_t)b * T_ * UP1 + (el - 1) * UP1 + ll] * K2;
        lossBuf[b] = -(aU + term) * LN2;
    }
}

// ---- Finalize: mean of per-batch losses ----
__global__ __launch_bounds__(64) void finalize_kernel(const float* __restrict__ lossBuf,
                                                      float* __restrict__ out) {
    if (threadIdx.x == 0) {
        float s = 0.f;
        for (int i = 0; i < B_; ++i) s += lossBuf[i];
        out[0] = s / (float)B_;
    }
}

extern "C" void kernel_launch(void* const* d_in, const int* in_sizes, int n_in,
                              void* d_out, int out_size, void* d_ws, size_t ws_size,
                              hipStream_t stream) {
    (void)in_sizes; (void)n_in; (void)out_size; (void)ws_size;
    const float* enc        = (const float*)d_in[0];
    const float* pred       = (const float*)d_in[1];
    const float* W_enc      = (const float*)d_in[2];
    const float* W_pred     = (const float*)d_in[3];
    const float* b_joint    = (const float*)d_in[4];
    const float* W_out      = (const float*)d_in[5];
    const float* b_out      = (const float*)d_in[6];
    const int*   labels     = (const int*)d_in[7];
    const int*   enc_lens   = (const int*)d_in[8];
    const int*   label_lens = (const int*)d_in[9];
    const int*   blank_id   = (const int*)d_in[10];

    float* ep  = (float*)d_ws;                      // B*T*J   = 1,048,576 f
    float* pp  = ep  + (size_t)B_ * T_ * J_;        // B*65*J  =   266,240 f
    float* blp = pp  + (size_t)B_ * UP1 * J_;       // B*T*65  =   133,120 f
    float* llp = blp + (size_t)B_ * T_ * UP1;       // B*T*64  =   131,072 f
    unsigned char* Wf = (unsigned char*)(llp + (size_t)B_ * T_ * U_);  // 512KB frag fp8
    float* Spart = (float*)(Wf + (size_t)V_ * J_);  // 4 * NCELL f32
    unsigned char* hG = (unsigned char*)(Spart + (size_t)4 * NCELL);   // NCELL*512 fp8
    float* lossBuf = (float*)(hG + (size_t)NCELL * 512);               // B_ f32
    float* Mbuf    = lossBuf + 64;                  // B_*8*65*66 f32 = 1.1 MB

    wt_kernel<<<dim3(V_ / 32, J_ / 32), dim3(256), 0, stream>>>(W_out, Wf);
    gemm_in<<<dim3((B_ * T_ + 31) / 32, J_ / 64), dim3(256), 0, stream>>>(
        enc, W_enc, b_joint, ep, B_ * T_);
    gemm_in<<<dim3((B_ * UP1 + 31) / 32, J_ / 64), dim3(256), 0, stream>>>(
        pred, W_pred, nullptr, pp, B_ * UP1);
    hgen_kernel<<<dim3(NCELL / 64), dim3(512), 0, stream>>>(ep, pp, hG);
    joint_mfma<<<dim3(NCELL / 64 * 4), dim3(256), 0, stream>>>(
        hG, Wf, b_out, labels, blank_id, Spart, blp, llp);
    pass2_kernel<<<dim3((NCELL + 255) / 256), dim3(256), 0, stream>>>(Spart, blp, llp);
    segscan_kernel<<<dim3(B_ * NSEG * 65), dim3(64), 0, stream>>>(blp, llp, enc_lens,
                                                                  Mbuf);
    apply_kernel<<<dim3(B_), dim3(64), 0, stream>>>(Mbuf, blp, enc_lens, label_lens,
                                                    lossBuf);
    finalize_kernel<<<dim3(1), dim3(64), 0, stream>>>(lossBuf, (float*)d_out);
}

// Round 19
// 267.970 us; speedup vs baseline: 1.4772x; 1.1729x over previous
//
#include <hip/hip_runtime.h>
#include <math.h>

#define B_   8
#define T_   256
#define U_   64
#define UP1  65
#define DE   640
#define J_   512
#define V_   1024
#define NCELL (B_ * T_ * UP1)
#define LOG0 -1e30f
#define NSEG 8
#define SEGLEN 32
#define MLD  66   // matrix column leading dim (65 rows + 1 pad)

typedef __attribute__((ext_vector_type(4))) float f32x4;
typedef __attribute__((ext_vector_type(8))) short short8;

__device__ __forceinline__ unsigned short f2bf(float x) {
    union { float f; unsigned int u; } c; c.f = x;
    unsigned int r = (c.u + 0x7fffu + ((c.u >> 16) & 1u)) >> 16;  // RNE
    return (unsigned short)r;
}

// ---------------- DPP wave64 scan/reduce helpers -------------------------------------
template<int CTRL, int RM>
__device__ __forceinline__ float dppz(float x) {
    return __builtin_bit_cast(float,
        __builtin_amdgcn_update_dpp(0, __builtin_bit_cast(int, x), CTRL, RM, 0xf, false));
}
template<int CTRL, int RM>
__device__ __forceinline__ float dpps(float x) {
    int xi = __builtin_bit_cast(int, x);
    return __builtin_bit_cast(float,
        __builtin_amdgcn_update_dpp(xi, xi, CTRL, RM, 0xf, false));
}
__device__ __forceinline__ float wave_prefix_sum(float v) {
    v += dppz<0x111, 0xf>(v);
    v += dppz<0x112, 0xf>(v);
    v += dppz<0x114, 0xf>(v);
    v += dppz<0x118, 0xf>(v);
    v += dppz<0x142, 0xa>(v);
    v += dppz<0x143, 0xc>(v);
    return v;
}
__device__ __forceinline__ float wave_max_all(float v) {
    v = fmaxf(v, dpps<0x111, 0xf>(v));
    v = fmaxf(v, dpps<0x112, 0xf>(v));
    v = fmaxf(v, dpps<0x114, 0xf>(v));
    v = fmaxf(v, dpps<0x118, 0xf>(v));
    v = fmaxf(v, dpps<0x142, 0xa>(v));
    v = fmaxf(v, dpps<0x143, 0xc>(v));
    return __builtin_bit_cast(float,
        __builtin_amdgcn_readlane(__builtin_bit_cast(int, v), 63));
}
__device__ __forceinline__ float rdlane(float v, int l) {
    return __builtin_bit_cast(float,
        __builtin_amdgcn_readlane(__builtin_bit_cast(int, v), l));
}

// LDS swizzle for fp8 hB: row m (512B rows), cb = column byte offset (8B granular).
__device__ __forceinline__ unsigned hb8(unsigned m, unsigned cb) {
    return m * 512u + (cb ^ ((m & 15u) << 3));
}

// ---- Kernel P: prep. Ranges: [0,160) wf2e, [160,320) wf2p, [320,960) enc->bf16,
// [960,1123) pred->bf16. Weight frag layout: short8 idx = (tl*20+kt)*64 + lane,
// element j -> (k = kt*32+lg*8+j, col = tl*16+ln).
__global__ __launch_bounds__(256) void prep_kernel(const float* __restrict__ We,
                                                   const float* __restrict__ Wp,
                                                   const float* __restrict__ enc,
                                                   const float* __restrict__ pred,
                                                   unsigned short* __restrict__ wf2e,
                                                   unsigned short* __restrict__ wf2p,
                                                   unsigned short* __restrict__ encB,
                                                   unsigned short* __restrict__ predB) {
    int bx = blockIdx.x, tid = threadIdx.x;
    if (bx < 320) {
        const float* W = (bx < 160) ? We : Wp;
        unsigned short* dst = (bx < 160) ? wf2e : wf2p;
        int gid = ((bx < 160) ? bx : bx - 160) * 256 + tid;   // 0..40959
        int lane = gid & 63, ktl = gid >> 6;
        int kt = ktl % 20, tl = ktl / 20;
        int lg = lane >> 4, ln = lane & 15;
        int col = tl * 16 + ln;
        short8 v;
#pragma unroll
        for (int j = 0; j < 8; ++j)
            v[j] = (short)f2bf(W[(size_t)(kt * 32 + lg * 8 + j) * J_ + col]);
        *(short8*)(dst + (size_t)gid * 8) = v;
    } else if (bx < 960) {
        int gid = (bx - 320) * 256 + tid;                     // enc: 163840 groups of 8
        const float* s = enc + (size_t)gid * 8;
        float4 a = *(const float4*)s, b = *(const float4*)(s + 4);
        short8 v;
        v[0] = (short)f2bf(a.x); v[1] = (short)f2bf(a.y);
        v[2] = (short)f2bf(a.z); v[3] = (short)f2bf(a.w);
        v[4] = (short)f2bf(b.x); v[5] = (short)f2bf(b.y);
        v[6] = (short)f2bf(b.z); v[7] = (short)f2bf(b.w);
        *(short8*)(encB + (size_t)gid * 8) = v;
    } else {
        int gid = (bx - 960) * 256 + tid;                     // pred: 41600 groups of 8
        if (gid < 41600) {
            const float* s = pred + (size_t)gid * 8;
            float4 a = *(const float4*)s, b = *(const float4*)(s + 4);
            short8 v;
            v[0] = (short)f2bf(a.x); v[1] = (short)f2bf(a.y);
            v[2] = (short)f2bf(a.z); v[3] = (short)f2bf(a.w);
            v[4] = (short)f2bf(b.x); v[5] = (short)f2bf(b.y);
            v[6] = (short)f2bf(b.z); v[7] = (short)f2bf(b.w);
            *(short8*)(predB + (size_t)gid * 8) = v;
        }
    }
}

// ---- Kernel A: bf16 MFMA input GEMM (enc & pred in one dispatch). 1 wave = 64x64. ----
// grid = (32 enc tiles + 9 pred tiles) x 8 col-tiles. No LDS, no barriers: A/B from L2.
__global__ __launch_bounds__(64) void gemm_mfma(const unsigned short* __restrict__ encB,
                                                const unsigned short* __restrict__ predB,
                                                const unsigned short* __restrict__ wf2e,
                                                const unsigned short* __restrict__ wf2p,
                                                const float* __restrict__ bj,
                                                float* __restrict__ ep,
                                                float* __restrict__ pp) {
    int rt = blockIdx.x, ct = blockIdx.y;
    int lane = threadIdx.x;
    const unsigned short* A;
    const short8* wp;
    float* C;
    const float* bias;
    int M, row0;
    if (rt < 32) { A = encB;  wp = (const short8*)wf2e; C = ep; bias = bj;      M = 2048; row0 = rt * 64; }
    else         { A = predB; wp = (const short8*)wf2p; C = pp; bias = nullptr; M = 520;  row0 = (rt - 32) * 64; }
    int lg = lane >> 4, ln = lane & 15;

    int r_[4];
#pragma unroll
    for (int mi = 0; mi < 4; ++mi) {
        int rr = row0 + mi * 16 + ln;
        r_[mi] = (rr < M) ? rr : (M - 1);        // clamp: finite garbage, stores guarded
    }

#define WIDX(NI, KT) (((size_t)((ct * 4 + (NI)) * 20 + (KT))) * 64 + lane)
    short8 bf[3][4], af[2][4];
#pragma unroll
    for (int ni = 0; ni < 4; ++ni) bf[0][ni] = wp[WIDX(ni, 0)];
#pragma unroll
    for (int ni = 0; ni < 4; ++ni) bf[1][ni] = wp[WIDX(ni, 1)];
#pragma unroll
    for (int mi = 0; mi < 4; ++mi)
        af[0][mi] = *(const short8*)(A + (size_t)r_[mi] * DE + lg * 8);

    f32x4 acc[4][4] = {};
#pragma unroll
    for (int kt = 0; kt < 20; ++kt) {
        const int cur3 = kt % 3;
        const int pf3  = (kt + 2) % 3;
        const int cur  = kt & 1, nxt = cur ^ 1;
#pragma unroll
        for (int ni = 0; ni < 4; ++ni) {
            if (kt < 18) bf[pf3][ni] = wp[WIDX(ni, kt + 2)];
            __builtin_amdgcn_s_setprio(1);
#pragma unroll
            for (int mi = 0; mi < 4; ++mi)
                acc[mi][ni] = __builtin_amdgcn_mfma_f32_16x16x32_bf16(
                    af[cur][mi], bf[cur3][ni], acc[mi][ni], 0, 0, 0);
            __builtin_amdgcn_s_setprio(0);
            if (ni == 1 && kt < 19) {
#pragma unroll
                for (int mi = 0; mi < 4; ++mi)
                    af[nxt][mi] = *(const short8*)(A + (size_t)r_[mi] * DE +
                                                   (kt + 1) * 32 + lg * 8);
            }
        }
    }
#undef WIDX

#pragma unroll
    for (int mi = 0; mi < 4; ++mi) {
#pragma unroll
        for (int r = 0; r < 4; ++r) {
            int row = row0 + mi * 16 + lg * 4 + r;
            if (row >= M) continue;
#pragma unroll
            for (int ni = 0; ni < 4; ++ni) {
                int col = ct * 64 + ni * 16 + ln;
                float v = acc[mi][ni][r];
                if (bias) v += bias[col];
                C[(size_t)row * J_ + col] = v;
            }
        }
    }
}

// ---- Kernel W: W_out[512][1024] -> fragment-major fp8(e4m3) Wf (round-6 K32 layout) --
__global__ __launch_bounds__(256) void wt_kernel(const float* __restrict__ W,
                                                 unsigned char* __restrict__ Wf) {
    __shared__ float tile[32][33];
    int tid = threadIdx.x;
    int tx = tid & 31, ty = tid >> 5;  // 32x8
    int v0 = blockIdx.x * 32, k0 = blockIdx.y * 32;
#pragma unroll
    for (int i = 0; i < 4; ++i)
        tile[ty + i * 8][tx] = W[(size_t)(k0 + ty + i * 8) * V_ + v0 + tx];
    __syncthreads();
    if (tid < 128) {
        int vl = tid >> 2, lg = tid & 3;
        int v  = v0 + vl;
        float x[8];
#pragma unroll
        for (int j = 0; j < 8; ++j) x[j] = tile[lg * 8 + j][vl];
        int lo = 0, hi = 0;
        lo = __builtin_amdgcn_cvt_pk_fp8_f32(x[0], x[1], lo, false);
        lo = __builtin_amdgcn_cvt_pk_fp8_f32(x[2], x[3], lo, true);
        hi = __builtin_amdgcn_cvt_pk_fp8_f32(x[4], x[5], hi, false);
        hi = __builtin_amdgcn_cvt_pk_fp8_f32(x[6], x[7], hi, true);
        int tl = v >> 4, ln = v & 15, kt = k0 >> 5;
        *(int2*)(Wf + tl * 8192 + kt * 512 + (lg * 16 + ln) * 8) = make_int2(lo, hi);
    }
}

// ---- Kernel H: h = tanh(ep+pp) fp8, pre-swizzled, OUTPUT-LINEAR (coalesced writes) ---
__global__ __launch_bounds__(512) void hgen_kernel(const float* __restrict__ ep,
                                                   const float* __restrict__ pp,
                                                   unsigned char* __restrict__ hG) {
    int tid  = threadIdx.x;
    int tile = blockIdx.x;
    unsigned char* outb = hG + (size_t)tile * 32768;
#pragma unroll
    for (int i = 0; i < 4; ++i) {
        int g   = tid + i * 512;
        int row = g >> 5;
        int lin9 = (g & 31) * 16;
        unsigned swz = ((unsigned)(row & 15)) << 3;
        int k0   = lin9 ^ (int)(swz & ~8u);
        int swap = row & 1;
        int cell = tile * 64 + row;
        unsigned epRow = (unsigned)cell / 65u;
        int u = cell - (int)epRow * 65;
        int b = (int)(epRow >> 8);
        const float* epr = ep + (size_t)epRow * J_ + k0;
        const float* ppr = pp + (size_t)(b * UP1 + u) * J_ + k0;
        float t[16];
#pragma unroll
        for (int q = 0; q < 4; ++q) {
            float4 e = *(const float4*)(epr + q * 4);
            float4 p = *(const float4*)(ppr + q * 4);
            float xs[4] = {e.x + p.x, e.y + p.y, e.z + p.z, e.w + p.w};
#pragma unroll
            for (int j = 0; j < 4; ++j) {
                float e2 = __expf(2.f * xs[j]);
                t[q * 4 + j] = 1.f - 2.f / (e2 + 1.f);
            }
        }
        int a0 = 0, a1 = 0, b0 = 0, b1 = 0;
        a0 = __builtin_amdgcn_cvt_pk_fp8_f32(t[0], t[1], a0, false);
        a0 = __builtin_amdgcn_cvt_pk_fp8_f32(t[2], t[3], a0, true);
        a1 = __builtin_amdgcn_cvt_pk_fp8_f32(t[4], t[5], a1, false);
        a1 = __builtin_amdgcn_cvt_pk_fp8_f32(t[6], t[7], a1, true);
        b0 = __builtin_amdgcn_cvt_pk_fp8_f32(t[8], t[9], b0, false);
        b0 = __builtin_amdgcn_cvt_pk_fp8_f32(t[10], t[11], b0, true);
        b1 = __builtin_amdgcn_cvt_pk_fp8_f32(t[12], t[13], b1, false);
        b1 = __builtin_amdgcn_cvt_pk_fp8_f32(t[14], t[15], b1, true);
        int4 w = swap ? make_int4(b0, b1, a0, a1) : make_int4(a0, a1, b0, b1);
        *(int4*)(outb + g * 16) = w;
    }
}

// ---- Kernel B: fp8-K32 joint, reg staging, XCD-grouped, (256,3) known-good ----------
__global__ __launch_bounds__(256, 3) void joint_mfma(const unsigned char* __restrict__ hG,
                                                     const unsigned char* __restrict__ Wf,
                                                     const float* __restrict__ bout,
                                                     const int* __restrict__ labels,
                                                     const int* __restrict__ pblank,
                                                     float* __restrict__ Spart,
                                                     float* __restrict__ blp,
                                                     float* __restrict__ llp) {
    __shared__ __align__(16) unsigned char hB[64 * 512];
    __shared__ float ps[4][64];

    int tid  = threadIdx.x;
    int bx   = blockIdx.x;
    int tile = (bx >> 5) * 8 + (bx & 7);
    int bh   = (bx >> 3) & 3;
    int c0   = tile * 64;
    int wc = tid >> 6, lane = tid & 63;
    int lg = lane >> 4, ln = lane & 15;

    const long* wfbL = (const long*)Wf + (((bh << 4) + (wc << 2)) << 10) + lane;

    long bf[3][4];
    long af[2][4];

    // ---- stage: linear 32KB reg copy hG -> LDS, bf prologue overlapped ----
    {
        int4 v[8];
        const int4* g = (const int4*)(hG + (size_t)tile * 32768) + tid;
#pragma unroll
        for (int i = 0; i < 8; ++i) v[i] = g[i * 256];
#pragma unroll
        for (int ni = 0; ni < 4; ++ni) bf[0][ni] = wfbL[ni * 1024];
#pragma unroll
        for (int ni = 0; ni < 4; ++ni) bf[1][ni] = wfbL[ni * 1024 + 64];
#pragma unroll
        for (int i = 0; i < 8; ++i) ((int4*)hB)[tid + i * 256] = v[i];
    }
    __syncthreads();

    f32x4 acc[4][4] = {};
#pragma unroll
    for (int mi = 0; mi < 4; ++mi)
        af[0][mi] = *(const long*)(hB + hb8((unsigned)(mi * 16 + ln), (unsigned)(lg * 8)));

#pragma unroll
    for (int kt = 0; kt < 16; ++kt) {
        const int cur3 = kt % 3;
        const int pf3  = (kt + 2) % 3;
        const int cur  = kt & 1, nxt = cur ^ 1;
#pragma unroll
        for (int ni = 0; ni < 4; ++ni) {
            if (kt < 14) bf[pf3][ni] = wfbL[ni * 1024 + (kt + 2) * 64];
            __builtin_amdgcn_s_setprio(1);
#pragma unroll
            for (int mi = 0; mi < 4; ++mi)
                acc[mi][ni] = __builtin_amdgcn_mfma_f32_16x16x32_fp8_fp8(
                    af[cur][mi], bf[cur3][ni], acc[mi][ni], 0, 0, 0);
            __builtin_amdgcn_s_setprio(0);
            if (ni == 1 && kt < 15) {
#pragma unroll
                for (int mi = 0; mi < 4; ++mi) {
                    unsigned m  = (unsigned)(mi * 16 + ln);
                    unsigned cb = (unsigned)((kt + 1) * 32 + lg * 8);
                    af[nxt][mi] = *(const long*)(hB + hb8(m, cb));
                }
            }
        }
    }

    // ---- epilogue: bias, partial exp-sum over this quarter's 256 cols, raw gather ----
    float bo[4];
#pragma unroll
    for (int ni = 0; ni < 4; ++ni) bo[ni] = bout[(bh << 8) + (wc << 6) + (ni << 4) + ln];
#pragma unroll
    for (int mi = 0; mi < 4; ++mi)
#pragma unroll
        for (int ni = 0; ni < 4; ++ni)
#pragma unroll
            for (int r = 0; r < 4; ++r) acc[mi][ni][r] += bo[ni];

#pragma unroll
    for (int mi = 0; mi < 4; ++mi) {
#pragma unroll
        for (int r = 0; r < 4; ++r) {
            float s = 0.f;
#pragma unroll
            for (int ni = 0; ni < 4; ++ni) s += __expf(acc[mi][ni][r]);
            s += __shfl_xor(s, 1);
            s += __shfl_xor(s, 2);
            s += __shfl_xor(s, 4);
            s += __shfl_xor(s, 8);
            if (ln == 0) ps[wc][mi * 16 + lg * 4 + r] = s;
        }
    }
    __syncthreads();
    if (tid < 64) {
        float S = ps[0][tid] + ps[1][tid] + ps[2][tid] + ps[3][tid];
        Spart[(size_t)bh * NCELL + c0 + tid] = S;
    }

    int blank = *pblank;
#pragma unroll
    for (int mi = 0; mi < 4; ++mi) {
#pragma unroll
        for (int r = 0; r < 4; ++r) {
            int row  = mi * 16 + lg * 4 + r;
            int cell = c0 + row;
            unsigned epRow = (unsigned)cell / 65u;
            int u = cell - (int)epRow * 65;
            int b = (int)(epRow >> 8);
            int lab = (u < U_) ? labels[(b << 6) + u] : -1;
#pragma unroll
            for (int ni = 0; ni < 4; ++ni) {
                int col = (bh << 8) + (wc << 6) + (ni << 4) + ln;
                float lgt = acc[mi][ni][r];
                if (col == blank) blp[cell] = lgt;                            // raw
                if (col == lab)   llp[(size_t)(((int)epRow << 6) + u)] = lgt; // raw
            }
        }
    }
}

// ---- Pass 2: lse = log(S0+S1+S2+S3); subtract from raw blank/label logits ----
__global__ __launch_bounds__(256) void pass2_kernel(const float* __restrict__ Spart,
                                                    float* __restrict__ blp,
                                                    float* __restrict__ llp) {
    int idx = blockIdx.x * 256 + threadIdx.x;
    if (idx >= NCELL) return;
    float lse = __logf(Spart[idx] + Spart[NCELL + idx] +
                       Spart[2 * NCELL + idx] + Spart[3 * NCELL + idx]);
    blp[idx] -= lse;
    unsigned epRow = (unsigned)idx / 65u;
    int u = idx - (int)epRow * 65;
    if (u < U_) llp[(size_t)((epRow << 6) + u)] -= lse;
}

// ------- Kernel S1: segment-operator build (R18: batch-preload + full unroll) ---------
__global__ __launch_bounds__(64) void segscan_kernel(const float* __restrict__ blp,
                                                     const float* __restrict__ llp,
                                                     const int* __restrict__ enc_lens,
                                                     float* __restrict__ Mbuf) {
    const float K2 = 1.4426950408889634f;
    int idx  = blockIdx.x;
    int v    = idx % 65;
    int seg  = (idx / 65) % NSEG;
    int b    = idx / (65 * NSEG);
    int lane = threadIdx.x;
    int el   = enc_lens[b];
    int t0   = seg * SEGLEN;
    if (t0 >= el) return;
    const float* bb = blp + (size_t)b * T_ * UP1;
    const float* lb = llp + (size_t)b * T_ * U_;

    float bvK[SEGLEN], lvK[SEGLEN], b64K[SEGLEN];
#pragma unroll
    for (int j = 0; j < SEGLEN; ++j) {
        int t  = t0 + j;
        int tc = (t < el) ? t : (el - 1);
        bvK[j]  = bb[tc * UP1 + lane] * K2;
        b64K[j] = bb[tc * UP1 + 64] * K2;
        lvK[j]  = lb[tc * U_ + lane] * K2;
    }

    float alpha   = (lane == v) ? 0.f : LOG0;
    float alpha64 = (v == 64) ? 0.f : LOG0;

#pragma unroll
    for (int j = 0; j < SEGLEN; ++j) {
        if (t0 + j < el) {
            float P = wave_prefix_sum(lvK[j]);
            float L = dpps<0x111, 0xf>(P);
            float P15 = rdlane(P, 15), P31 = rdlane(P, 31), P47 = rdlane(P, 47);
            if (lane == 0)  L = 0.f;
            if (lane == 16) L = P15;
            if (lane == 32) L = P31;
            if (lane == 48) L = P47;
            float P63 = rdlane(P, 63);
            float x   = alpha + bvK[j] - L;
            float x64 = alpha64 + b64K[j] - P63;
            float M = fmaxf(wave_max_all(x), x64);
            float S = wave_prefix_sum(__builtin_amdgcn_exp2f(x - M));
            float S63 = rdlane(S, 63);
            alpha   = L + M + __builtin_amdgcn_logf(S);
            alpha64 = P63 + M +
                      __builtin_amdgcn_logf(S63 + __builtin_amdgcn_exp2f(x64 - M));
        }
    }

    float* col = Mbuf + ((size_t)((b * NSEG + seg) * 65 + v)) * MLD;
    col[lane] = fmaxf(alpha, LOG0);
    if (lane == 0) col[64] = fmaxf(alpha64, LOG0);
}

// ------- Kernel S2: apply segment operators sequentially. 1 block/batch, 1 wave. ------
__global__ __launch_bounds__(64) void apply_kernel(const float* __restrict__ Mbuf,
                                                   const float* __restrict__ blp,
                                                   const int* __restrict__ enc_lens,
                                                   const int* __restrict__ label_lens,
                                                   float* __restrict__ lossBuf) {
    __shared__ float Ml[65 * MLD];
    __shared__ float xv[66];
    const float K2  = 1.4426950408889634f;
    const float LN2 = 0.6931471805599453f;
    int b    = blockIdx.x;
    int lane = threadIdx.x;
    int el = enc_lens[b];
    int ll = label_lens[b];

    xv[lane] = (lane == 0) ? 0.f : LOG0;
    if (lane == 0) xv[64] = LOG0;
    __syncthreads();

    for (int seg = 0; seg < NSEG; ++seg) {
        if (seg * SEGLEN >= el) break;
        const float* src = Mbuf + (size_t)((b * NSEG + seg) * 65) * MLD;
        for (int i = lane; i < 65 * MLD; i += 64) Ml[i] = src[i];
        __syncthreads();
        float m = LOG0;
#pragma unroll 5
        for (int vv = 0; vv < 65; ++vv) m = fmaxf(m, Ml[vv * MLD + lane] + xv[vv]);
        m = fmaxf(m, LOG0);
        float s = 0.f;
#pragma unroll 5
        for (int vv = 0; vv < 65; ++vv)
            s += __builtin_amdgcn_exp2f(Ml[vv * MLD + lane] + xv[vv] - m);
        float y = fmaxf(m + __builtin_amdgcn_logf(s), LOG0);
        float t64  = xv[lane] + Ml[lane * MLD + 64];
        float t64b = xv[64] + Ml[64 * MLD + 64];
        float m64 = fmaxf(fmaxf(wave_max_all(t64), t64b), LOG0);
        float s64 = rdlane(wave_prefix_sum(__builtin_amdgcn_exp2f(t64 - m64)), 63);
        s64 += __builtin_amdgcn_exp2f(t64b - m64);
        float y64 = fmaxf(m64 + __builtin_amdgcn_logf(s64), LOG0);
        __syncthreads();
        xv[lane] = y;
        if (lane == 0) xv[64] = y64;
        __syncthreads();
    }

    if (lane == 0) {
        float aU = (ll < 64) ? xv[ll] : xv[64];
        float term = blp[(size_t)b * T_ * UP1 + (el - 1) * UP1 + ll] * K2;
        lossBuf[b] = -(aU + term) * LN2;
    }
}

// ---- Finalize: mean of per-batch losses ----
__global__ __launch_bounds__(64) void finalize_kernel(const float* __restrict__ lossBuf,
                                                      float* __restrict__ out) {
    if (threadIdx.x == 0) {
        float s = 0.f;
        for (int i = 0; i < B_; ++i) s += lossBuf[i];
        out[0] = s / (float)B_;
    }
}

extern "C" void kernel_launch(void* const* d_in, const int* in_sizes, int n_in,
                              void* d_out, int out_size, void* d_ws, size_t ws_size,
                              hipStream_t stream) {
    (void)in_sizes; (void)n_in; (void)out_size; (void)ws_size;
    const float* enc        = (const float*)d_in[0];
    const float* pred       = (const float*)d_in[1];
    const float* W_enc      = (const float*)d_in[2];
    const float* W_pred     = (const float*)d_in[3];
    const float* b_joint    = (const float*)d_in[4];
    const float* W_out      = (const float*)d_in[5];
    const float* b_out      = (const float*)d_in[6];
    const int*   labels     = (const int*)d_in[7];
    const int*   enc_lens   = (const int*)d_in[8];
    const int*   label_lens = (const int*)d_in[9];
    const int*   blank_id   = (const int*)d_in[10];

    float* ep  = (float*)d_ws;                      // B*T*J   = 1,048,576 f
    float* pp  = ep  + (size_t)B_ * T_ * J_;        // B*65*J  =   266,240 f
    float* blp = pp  + (size_t)B_ * UP1 * J_;       // B*T*65  =   133,120 f
    float* llp = blp + (size_t)B_ * T_ * UP1;       // B*T*64  =   131,072 f
    unsigned char* Wf = (unsigned char*)(llp + (size_t)B_ * T_ * U_);  // 512KB frag fp8
    float* Spart = (float*)(Wf + (size_t)V_ * J_);  // 4 * NCELL f32
    unsigned char* hG = (unsigned char*)(Spart + (size_t)4 * NCELL);   // NCELL*512 fp8
    float* lossBuf = (float*)(hG + (size_t)NCELL * 512);               // B_ f32
    float* Mbuf    = lossBuf + 64;                  // B_*8*65*66 f32 = 1.1 MB

    // bf16 staging buffers alias hG (dead before hgen writes it)
    unsigned short* encB  = (unsigned short*)hG;            // 2048*640 bf16
    unsigned short* predB = encB + (size_t)2048 * DE;       // 520*640 bf16
    unsigned short* wf2e  = predB + (size_t)520 * DE;       // 640*512 bf16 frag-major
    unsigned short* wf2p  = wf2e + (size_t)DE * J_;

    wt_kernel<<<dim3(V_ / 32, J_ / 32), dim3(256), 0, stream>>>(W_out, Wf);
    prep_kernel<<<dim3(1123), dim3(256), 0, stream>>>(W_enc, W_pred, enc, pred,
                                                      wf2e, wf2p, encB, predB);
    gemm_mfma<<<dim3(41, 8), dim3(64), 0, stream>>>(encB, predB, wf2e, wf2p, b_joint,
                                                    ep, pp);
    hgen_kernel<<<dim3(NCELL / 64), dim3(512), 0, stream>>>(ep, pp, hG);
    joint_mfma<<<dim3(NCELL / 64 * 4), dim3(256), 0, stream>>>(
        hG, Wf, b_out, labels, blank_id, Spart, blp, llp);
    pass2_kernel<<<dim3((NCELL + 255) / 256), dim3(256), 0, stream>>>(Spart, blp, llp);
    segscan_kernel<<<dim3(B_ * NSEG * 65), dim3(64), 0, stream>>>(blp, llp, enc_lens,
                                                                  Mbuf);
    apply_kernel<<<dim3(B_), dim3(64), 0, stream>>>(Mbuf, blp, enc_lens, label_lens,
                                                    lossBuf);
    finalize_kernel<<<dim3(1), dim3(64), 0, stream>>>(lossBuf, (float*)d_out);
}